// Round 1
// baseline (602.738 us; speedup 1.0000x reference)
//
#include <hip/hip_runtime.h>

// Problem constants
// B=4, P=2048, N=8192, QD=CD=INNER=512, HEADS=8, DH=64, HC=WC=32, L=1024
// STRIDE=8 -> 17x17 clipped rectangle mask; PE_H=64

typedef __attribute__((ext_vector_type(8))) short bf16x8;
typedef __attribute__((ext_vector_type(4))) float f32x4;

__device__ __forceinline__ unsigned short f2bf(float x) {
  union { float f; unsigned int u; } v; v.f = x;
  unsigned int r = v.u + 0x7FFFu + ((v.u >> 16) & 1u);  // RNE
  return (unsigned short)(r >> 16);
}

// ---- prep: A_q = bf16(feats + pos_embedding[coords//8]) ----
__global__ __launch_bounds__(256) void prep_q(const float* __restrict__ feats,
                                              const int* __restrict__ coords,
                                              const float* __restrict__ pos_emb,
                                              unsigned short* __restrict__ Aq) {
  int i = blockIdx.x * 256 + threadIdx.x;     // < 8192*512
  int q = i >> 9, k = i & 511;
  int rc0 = coords[2 * q] >> 3;
  int rc1 = coords[2 * q + 1] >> 3;
  Aq[i] = f2bf(feats[i] + pos_emb[(size_t)((rc0 << 6) + rc1) * 512 + k]);
}

// ---- prep: A_ctx = bf16(context_emb + context_pos_embedding) ----
__global__ __launch_bounds__(256) void prep_ctx(const float* __restrict__ ctx,
                                                const float* __restrict__ ctx_pos,
                                                unsigned short* __restrict__ Actx) {
  int i = blockIdx.x * 256 + threadIdx.x;     // < 4096*512
  int bl = i >> 9, k = i & 511;
  int ll = bl & 1023;
  Actx[i] = f2bf(ctx[i] + ctx_pos[(size_t)(ll << 9) + k]);
}

// ---- prep: transpose weights to N-major bf16 (Wt[n][k] = W[k][n]) ----
__global__ __launch_bounds__(256) void prep_w(const float* __restrict__ Wq, const float* __restrict__ Wk,
                                              const float* __restrict__ Wv, const float* __restrict__ Wo,
                                              unsigned short* __restrict__ Wqt, unsigned short* __restrict__ Wkt,
                                              unsigned short* __restrict__ Wvt, unsigned short* __restrict__ Wot) {
  int i = blockIdx.x * 256 + threadIdx.x;     // < 4*512*512
  int wsel = i >> 18;
  int r = i & 262143;
  int k = r >> 9, n = r & 511;
  const float* W = (wsel == 0) ? Wq : (wsel == 1) ? Wk : (wsel == 2) ? Wv : Wo;
  unsigned short* Wt = (wsel == 0) ? Wqt : (wsel == 1) ? Wkt : (wsel == 2) ? Wvt : Wot;
  Wt[n * 512 + k] = f2bf(W[r]);
}

// ---- bf16 MFMA GEMM: C[M x 512] = A[M x 512] @ Bt[512 x 512]^T (+bias) ----
// 128x128 tile, BK=32, 4 waves (2x2 of 64x64), fp32 accumulate.
__global__ __launch_bounds__(256) void gemm_bt(const unsigned short* __restrict__ A,
                                               const unsigned short* __restrict__ Bt,
                                               float* __restrict__ C,
                                               const float* __restrict__ bias) {
  __shared__ unsigned short As[128][40];   // +8 pad: 80B rows, 16B aligned
  __shared__ unsigned short Bs[128][40];
  const int t = threadIdx.x;
  const int l = t & 63;
  const int wid = t >> 6;
  const int wr = (wid >> 1) << 6;
  const int wc = (wid & 1) << 6;
  const long tm = (long)blockIdx.x * 128;
  const long tn = (long)blockIdx.y * 128;
  f32x4 acc[4][4] = {};
  const int lr = l & 15;
  const int lk = (l >> 4) << 3;
  for (int k0 = 0; k0 < 512; k0 += 32) {
#pragma unroll
    for (int p = 0; p < 2; ++p) {
      int e = t + (p << 8);
      int row = e >> 2;
      int kg = (e & 3) << 3;
      *(int4*)(&As[row][kg]) = *(const int4*)(A + (tm + row) * 512 + k0 + kg);
      *(int4*)(&Bs[row][kg]) = *(const int4*)(Bt + (tn + row) * 512 + k0 + kg);
    }
    __syncthreads();
    bf16x8 af[4], bfr[4];
#pragma unroll
    for (int i = 0; i < 4; ++i) af[i]  = *(const bf16x8*)(&As[wr + i * 16 + lr][lk]);
#pragma unroll
    for (int i = 0; i < 4; ++i) bfr[i] = *(const bf16x8*)(&Bs[wc + i * 16 + lr][lk]);
#pragma unroll
    for (int mi = 0; mi < 4; ++mi)
#pragma unroll
      for (int ni = 0; ni < 4; ++ni)
        acc[mi][ni] = __builtin_amdgcn_mfma_f32_16x16x32_bf16(af[mi], bfr[ni], acc[mi][ni], 0, 0, 0);
    __syncthreads();
  }
  const int lq = (l >> 4) << 2;
#pragma unroll
  for (int mi = 0; mi < 4; ++mi) {
#pragma unroll
    for (int ni = 0; ni < 4; ++ni) {
      long col = tn + wc + ni * 16 + lr;
      float bv = bias ? bias[col] : 0.0f;
      long r0 = tm + wr + mi * 16 + lq;
#pragma unroll
      for (int r = 0; r < 4; ++r)
        C[(r0 + r) * 512 + col] = acc[mi][ni][r] + bv;
    }
  }
}

// ---- transpose K to d-major: Ktr[b][h][d][l] = Kbuf[b*1024+l][h*64+d] ----
__global__ __launch_bounds__(256) void transpose_k(const float* __restrict__ Kbuf,
                                                   float* __restrict__ Ktr) {
  int i = blockIdx.x * 256 + threadIdx.x;     // < 4096*512
  int bl = i >> 9, n = i & 511;
  int b = bl >> 10, ll = bl & 1023;
  int h = n >> 6, d = n & 63;
  Ktr[(size_t)((b * 8 + h) * 64 + d) * 1024 + ll] = Kbuf[i];
}

// ---- masked attention: one wave per (query, head) ----
__global__ __launch_bounds__(256) void attn_kernel(const float* __restrict__ Q,
                                                   const float* __restrict__ Ktr,
                                                   const float* __restrict__ V,
                                                   const int* __restrict__ coords,
                                                   float* __restrict__ O) {
  __shared__ float q_lds[4][64];
  __shared__ float p_lds[4][320];
  const int w = threadIdx.x >> 6, l = threadIdx.x & 63;
  const int qh = blockIdx.x * 4 + w;
  const int qi = qh >> 3, h = qh & 7;
  const int b = qi >> 11;
  const int cr = (int)rintf((float)coords[2 * qi] * 0.0625f);      // round-half-even, matches jnp.round
  const int cc = (int)rintf((float)coords[2 * qi + 1] * 0.0625f);
  const int rlo = max(0, cr - 8), rhi = min(31, cr + 8);
  const int clo = max(0, cc - 8), chi = min(31, cc + 8);
  const int nr = rhi - rlo + 1, ncc = chi - clo + 1;
  const int nrect = nr * ncc;                                      // 81..289, >= 81 > 64
  q_lds[w][l] = Q[(size_t)qi * 512 + h * 64 + l];
  __syncthreads();
  float s[5]; int jj[5];
#pragma unroll
  for (int ch = 0; ch < 5; ++ch) {
    int idx = l + (ch << 6);
    int ri = idx / ncc;
    int ci = idx - ri * ncc;
    int j = (rlo + ri) * 32 + (clo + ci);
    jj[ch] = (idx < nrect) ? j : 0;
    s[ch] = 0.0f;
  }
  const float* Kb = Ktr + (size_t)((b * 8 + h) * 64) * 1024;
  for (int d = 0; d < 64; ++d) {
    float qd = q_lds[w][d];
    const float* krow = Kb + (size_t)d * 1024;
#pragma unroll
    for (int ch = 0; ch < 5; ++ch) s[ch] = fmaf(qd, krow[jj[ch]], s[ch]);
  }
  float m = -3.4e38f;
#pragma unroll
  for (int ch = 0; ch < 5; ++ch) {
    bool val = (l + (ch << 6)) < nrect;
    s[ch] = val ? s[ch] * 0.125f : -3.4e38f;
    m = fmaxf(m, s[ch]);
  }
  for (int off = 32; off > 0; off >>= 1) m = fmaxf(m, __shfl_xor(m, off));
  float p[5];
  float sum = 0.0f;
#pragma unroll
  for (int ch = 0; ch < 5; ++ch) {
    bool val = (l + (ch << 6)) < nrect;
    p[ch] = val ? __expf(s[ch] - m) : 0.0f;
    sum += p[ch];
  }
  for (int off = 32; off > 0; off >>= 1) sum += __shfl_xor(sum, off);
  float inv = 1.0f / sum;
#pragma unroll
  for (int ch = 0; ch < 5; ++ch) p_lds[w][l + (ch << 6)] = p[ch] * inv;
  __syncthreads();
  float acc = 0.0f;
  const float* Vb = V + ((size_t)b * 1024) * 512 + h * 64 + l;
  int idx = 0;
  for (int ri = 0; ri < nr; ++ri) {
    int jrow = (rlo + ri) * 32 + clo;
    for (int ci = 0; ci < ncc; ++ci) {
      acc = fmaf(p_lds[w][idx++], Vb[(size_t)(jrow + ci) * 512], acc);
    }
  }
  O[(size_t)qi * 512 + h * 64 + l] = acc;
}

// ---- convert attention output to bf16 for final projection ----
__global__ __launch_bounds__(256) void conv_bf(const float* __restrict__ X,
                                               unsigned short* __restrict__ Y) {
  int i = blockIdx.x * 256 + threadIdx.x;     // < 8192*512
  Y[i] = f2bf(X[i]);
}

extern "C" void kernel_launch(void* const* d_in, const int* in_sizes, int n_in,
                              void* d_out, int out_size, void* d_ws, size_t ws_size,
                              hipStream_t stream) {
  (void)in_sizes; (void)n_in; (void)out_size; (void)ws_size;
  const float* feats   = (const float*)d_in[0];
  const int*   coords  = (const int*)d_in[1];
  const float* ctx     = (const float*)d_in[2];
  const float* Wq      = (const float*)d_in[3];
  const float* Wk      = (const float*)d_in[4];
  const float* Wv      = (const float*)d_in[5];
  const float* Wo      = (const float*)d_in[6];
  const float* bo      = (const float*)d_in[7];
  const float* pos_emb = (const float*)d_in[8];
  const float* ctx_pos = (const float*)d_in[9];
  float* out = (float*)d_out;
  char* ws = (char*)d_ws;

  unsigned short* Aq   = (unsigned short*)(ws);               // 8192*512*2  = 8,388,608
  unsigned short* Actx = (unsigned short*)(ws + 8388608);     // 4096*512*2  = 4,194,304
  unsigned short* Wqt  = (unsigned short*)(ws + 12582912);    // 512*512*2   =   524,288
  unsigned short* Wkt  = (unsigned short*)(ws + 13107200);
  unsigned short* Wvt  = (unsigned short*)(ws + 13631488);
  unsigned short* Wot  = (unsigned short*)(ws + 14155776);
  float* Qbuf = (float*)(ws + 14680064);                      // 8192*512*4  = 16,777,216
  float* Kbuf = (float*)(ws + 31457280);                      // 4096*512*4  =  8,388,608
  float* Vbuf = (float*)(ws + 39845888);                      //               8,388,608
  float* Ktr  = (float*)(ws + 48234496);                      //               8,388,608
  float* Oatt = (float*)(ws + 56623104);                      //              16,777,216 (end 73,400,320)
  unsigned short* Abf = Aq;  // reuse: A_q is dead after the Q projection

  prep_q  <<<16384, 256, 0, stream>>>(feats, coords, pos_emb, Aq);
  prep_ctx<<< 8192, 256, 0, stream>>>(ctx, ctx_pos, Actx);
  prep_w  <<< 4096, 256, 0, stream>>>(Wq, Wk, Wv, Wo, Wqt, Wkt, Wvt, Wot);

  gemm_bt<<<dim3(64, 4), 256, 0, stream>>>(Aq,   Wqt, Qbuf, nullptr);   // Q
  gemm_bt<<<dim3(32, 4), 256, 0, stream>>>(Actx, Wkt, Kbuf, nullptr);   // K
  gemm_bt<<<dim3(32, 4), 256, 0, stream>>>(Actx, Wvt, Vbuf, nullptr);   // V

  transpose_k<<<8192, 256, 0, stream>>>(Kbuf, Ktr);
  attn_kernel<<<16384, 256, 0, stream>>>(Qbuf, Ktr, Vbuf, coords, Oatt);

  conv_bf<<<16384, 256, 0, stream>>>(Oatt, Abf);
  gemm_bt<<<dim3(64, 4), 256, 0, stream>>>(Abf, Wot, out, bo);          // O + bias
}

// Round 2
// 157.358 us; speedup vs baseline: 3.8304x; 3.8304x over previous
//
#include <hip/hip_runtime.h>

// Problem constants
// B=4, P=2048, N=8192, QD=CD=INNER=512, HEADS=8, DH=64, HC=WC=32, L=1024
// STRIDE=8 -> 17x17 clipped rectangle mask; PE_H=64

typedef __attribute__((ext_vector_type(8))) short bf16x8;
typedef __attribute__((ext_vector_type(4))) float f32x4;

__device__ __forceinline__ unsigned short f2bf(float x) {
  union { float f; unsigned int u; } v; v.f = x;
  unsigned int r = v.u + 0x7FFFu + ((v.u >> 16) & 1u);  // RNE
  return (unsigned short)(r >> 16);
}

// ---- prep: A_q = bf16(feats + pos_embedding[coords//8]) ----
__global__ __launch_bounds__(256) void prep_q(const float* __restrict__ feats,
                                              const int* __restrict__ coords,
                                              const float* __restrict__ pos_emb,
                                              unsigned short* __restrict__ Aq) {
  int i = blockIdx.x * 256 + threadIdx.x;     // < 8192*512
  int q = i >> 9, k = i & 511;
  int rc0 = coords[2 * q] >> 3;
  int rc1 = coords[2 * q + 1] >> 3;
  Aq[i] = f2bf(feats[i] + pos_emb[(size_t)((rc0 << 6) + rc1) * 512 + k]);
}

// ---- prep: A_ctx = bf16(context_emb + context_pos_embedding) ----
__global__ __launch_bounds__(256) void prep_ctx(const float* __restrict__ ctx,
                                                const float* __restrict__ ctx_pos,
                                                unsigned short* __restrict__ Actx) {
  int i = blockIdx.x * 256 + threadIdx.x;     // < 4096*512
  int bl = i >> 9, k = i & 511;
  int ll = bl & 1023;
  Actx[i] = f2bf(ctx[i] + ctx_pos[(size_t)(ll << 9) + k]);
}

// ---- prep: transpose weights to N-major bf16 (Wt[n][k] = W[k][n]) ----
__global__ __launch_bounds__(256) void prep_w(const float* __restrict__ Wq, const float* __restrict__ Wk,
                                              const float* __restrict__ Wv, const float* __restrict__ Wo,
                                              unsigned short* __restrict__ Wqt, unsigned short* __restrict__ Wkt,
                                              unsigned short* __restrict__ Wvt, unsigned short* __restrict__ Wot) {
  int i = blockIdx.x * 256 + threadIdx.x;     // < 4*512*512
  int wsel = i >> 18;
  int r = i & 262143;
  int k = r >> 9, n = r & 511;
  const float* W = (wsel == 0) ? Wq : (wsel == 1) ? Wk : (wsel == 2) ? Wv : Wo;
  unsigned short* Wt = (wsel == 0) ? Wqt : (wsel == 1) ? Wkt : (wsel == 2) ? Wvt : Wot;
  Wt[n * 512 + k] = f2bf(W[r]);
}

// ---- bf16 MFMA GEMM (fp32 out + bias): C = A @ Bt^T ----
__global__ __launch_bounds__(256) void gemm_bt(const unsigned short* __restrict__ A,
                                               const unsigned short* __restrict__ Bt,
                                               float* __restrict__ C,
                                               const float* __restrict__ bias) {
  __shared__ unsigned short As[128][40];
  __shared__ unsigned short Bs[128][40];
  const int t = threadIdx.x;
  const int l = t & 63;
  const int wid = t >> 6;
  const int wr = (wid >> 1) << 6;
  const int wc = (wid & 1) << 6;
  const long tm = (long)blockIdx.x * 128;
  const long tn = (long)blockIdx.y * 128;
  f32x4 acc[4][4] = {};
  const int lr = l & 15;
  const int lk = (l >> 4) << 3;
  for (int k0 = 0; k0 < 512; k0 += 32) {
#pragma unroll
    for (int p = 0; p < 2; ++p) {
      int e = t + (p << 8);
      int row = e >> 2;
      int kg = (e & 3) << 3;
      *(int4*)(&As[row][kg]) = *(const int4*)(A + (tm + row) * 512 + k0 + kg);
      *(int4*)(&Bs[row][kg]) = *(const int4*)(Bt + (tn + row) * 512 + k0 + kg);
    }
    __syncthreads();
    bf16x8 af[4], bfr[4];
#pragma unroll
    for (int i = 0; i < 4; ++i) af[i]  = *(const bf16x8*)(&As[wr + i * 16 + lr][lk]);
#pragma unroll
    for (int i = 0; i < 4; ++i) bfr[i] = *(const bf16x8*)(&Bs[wc + i * 16 + lr][lk]);
#pragma unroll
    for (int mi = 0; mi < 4; ++mi)
#pragma unroll
      for (int ni = 0; ni < 4; ++ni)
        acc[mi][ni] = __builtin_amdgcn_mfma_f32_16x16x32_bf16(af[mi], bfr[ni], acc[mi][ni], 0, 0, 0);
    __syncthreads();
  }
  const int lq = (l >> 4) << 2;
#pragma unroll
  for (int mi = 0; mi < 4; ++mi) {
#pragma unroll
    for (int ni = 0; ni < 4; ++ni) {
      long col = tn + wc + ni * 16 + lr;
      float bv = bias ? bias[col] : 0.0f;
      long r0 = tm + wr + mi * 16 + lq;
#pragma unroll
      for (int r = 0; r < 4; ++r)
        C[(r0 + r) * 512 + col] = acc[mi][ni][r] + bv;
    }
  }
}

// ---- bf16 MFMA GEMM (bf16 out, no bias): C = A @ Bt^T ----
__global__ __launch_bounds__(256) void gemm_bt_bf(const unsigned short* __restrict__ A,
                                                  const unsigned short* __restrict__ Bt,
                                                  unsigned short* __restrict__ C) {
  __shared__ unsigned short As[128][40];
  __shared__ unsigned short Bs[128][40];
  const int t = threadIdx.x;
  const int l = t & 63;
  const int wid = t >> 6;
  const int wr = (wid >> 1) << 6;
  const int wc = (wid & 1) << 6;
  const long tm = (long)blockIdx.x * 128;
  const long tn = (long)blockIdx.y * 128;
  f32x4 acc[4][4] = {};
  const int lr = l & 15;
  const int lk = (l >> 4) << 3;
  for (int k0 = 0; k0 < 512; k0 += 32) {
#pragma unroll
    for (int p = 0; p < 2; ++p) {
      int e = t + (p << 8);
      int row = e >> 2;
      int kg = (e & 3) << 3;
      *(int4*)(&As[row][kg]) = *(const int4*)(A + (tm + row) * 512 + k0 + kg);
      *(int4*)(&Bs[row][kg]) = *(const int4*)(Bt + (tn + row) * 512 + k0 + kg);
    }
    __syncthreads();
    bf16x8 af[4], bfr[4];
#pragma unroll
    for (int i = 0; i < 4; ++i) af[i]  = *(const bf16x8*)(&As[wr + i * 16 + lr][lk]);
#pragma unroll
    for (int i = 0; i < 4; ++i) bfr[i] = *(const bf16x8*)(&Bs[wc + i * 16 + lr][lk]);
#pragma unroll
    for (int mi = 0; mi < 4; ++mi)
#pragma unroll
      for (int ni = 0; ni < 4; ++ni)
        acc[mi][ni] = __builtin_amdgcn_mfma_f32_16x16x32_bf16(af[mi], bfr[ni], acc[mi][ni], 0, 0, 0);
    __syncthreads();
  }
  const int lq = (l >> 4) << 2;
#pragma unroll
  for (int mi = 0; mi < 4; ++mi) {
#pragma unroll
    for (int ni = 0; ni < 4; ++ni) {
      long col = tn + wc + ni * 16 + lr;
      long r0 = tm + wr + mi * 16 + lq;
#pragma unroll
      for (int r = 0; r < 4; ++r)
        C[(r0 + r) * 512 + col] = f2bf(acc[mi][ni][r]);
    }
  }
}

// ---- transpose V to d-major bf16: Vt[(bh*64+d)*1024 + j] = Vb[(b*1024+j)*512 + h*64+d] ----
__global__ __launch_bounds__(256) void vt_tile(const unsigned short* __restrict__ Vb,
                                               unsigned short* __restrict__ Vt) {
  __shared__ unsigned short tile[64][68];
  int bh = blockIdx.x >> 4, jt = blockIdx.x & 15;
  int b = bh >> 3, h = bh & 7;
  int t = threadIdx.x;
#pragma unroll
  for (int i = 0; i < 16; ++i) {
    int e = t + i * 256;          // 0..4095
    int jj = e >> 6, d = e & 63;
    tile[jj][d] = Vb[((long)(b * 1024 + jt * 64 + jj)) * 512 + h * 64 + d];
  }
  __syncthreads();
#pragma unroll
  for (int i = 0; i < 16; ++i) {
    int e = t + i * 256;
    int j = e & 63, d = e >> 6;
    Vt[((long)(bh * 64 + d)) * 1024 + jt * 64 + j] = tile[j][d];
  }
}

// ---- MFMA masked flash attention ----
// grid (16, 32): x = q-tile of 128 (4 waves x 32 q), y = b*8+h. Sweep 16 key-tiles of 64.
__global__ __launch_bounds__(256) void attn_mfma(const unsigned short* __restrict__ Qb,
                                                 const unsigned short* __restrict__ Kb,
                                                 const unsigned short* __restrict__ Vt,
                                                 const int* __restrict__ coords,
                                                 unsigned short* __restrict__ Abf) {
  __shared__ unsigned short Plds[4][32][72];  // per wave: 32 q x 64 keys (+8 pad)
  const int t = threadIdx.x;
  const int w = t >> 6, l = t & 63;
  const int g = l >> 4, lc = l & 15;
  const int bh = blockIdx.y; const int b = bh >> 3, h = bh & 7;
  const int qloc0 = blockIdx.x * 128 + w * 32;       // query within batch
  const long qrow0 = (long)b * 2048 + qloc0;         // row in [8192]

  // packed rect bounds for the 8 query-rows this lane touches (qf in {0,1}, r in {0..3})
  int pb[8];
#pragma unroll
  for (int qf = 0; qf < 2; ++qf)
#pragma unroll
    for (int r = 0; r < 4; ++r) {
      long qg = qrow0 + qf * 16 + g * 4 + r;
      int cr = (int)rintf((float)coords[2 * qg] * 0.0625f);      // round-half-even = jnp.round
      int cc = (int)rintf((float)coords[2 * qg + 1] * 0.0625f);
      int rlo = max(0, cr - 8), rhi = min(31, cr + 8);
      int clo = max(0, cc - 8), chi = min(31, cc + 8);
      pb[qf * 4 + r] = rlo | ((rhi - rlo) << 8) | (clo << 16) | ((chi - clo) << 24);
    }

  // Q fragments (A-layout: row = lc, k-chunk = g*8)
  bf16x8 qfr[2][2];
#pragma unroll
  for (int qf = 0; qf < 2; ++qf)
#pragma unroll
    for (int dc = 0; dc < 2; ++dc)
      qfr[qf][dc] = *(const bf16x8*)(Qb + (qrow0 + qf * 16 + lc) * 512 + h * 64 + dc * 32 + g * 8);

  f32x4 po[2][4] = {};   // O accum [qf][df], C-layout rows = queries
  float m_run[8], l_run[8];
#pragma unroll
  for (int i = 0; i < 8; ++i) { m_run[i] = -1e30f; l_run[i] = 0.0f; }

  const unsigned short* Kbb = Kb + ((long)b * 1024) * 512 + h * 64;
  const unsigned short* Vtb = Vt + ((long)bh * 64) * 1024;

  for (int kb = 0; kb < 1024; kb += 64) {
    // K fragments (B-layout: row = key = lc)
    bf16x8 kfr[4][2];
#pragma unroll
    for (int kf = 0; kf < 4; ++kf)
#pragma unroll
      for (int dc = 0; dc < 2; ++dc)
        kfr[kf][dc] = *(const bf16x8*)(Kbb + (long)(kb + kf * 16 + lc) * 512 + dc * 32 + g * 8);
    // V^T fragments for PV (B-layout: row = d = lc, k = key chunk)
    bf16x8 vfr[4][2];
#pragma unroll
    for (int df = 0; df < 4; ++df)
#pragma unroll
      for (int kc = 0; kc < 2; ++kc)
        vfr[df][kc] = *(const bf16x8*)(Vtb + (long)(df * 16 + lc) * 1024 + kb + kc * 32 + g * 8);

    // S = Q K^T
    f32x4 sv[2][4];
#pragma unroll
    for (int qf = 0; qf < 2; ++qf)
#pragma unroll
      for (int kf = 0; kf < 4; ++kf) {
        f32x4 a = {};
        a = __builtin_amdgcn_mfma_f32_16x16x32_bf16(qfr[qf][0], kfr[kf][0], a, 0, 0, 0);
        a = __builtin_amdgcn_mfma_f32_16x16x32_bf16(qfr[qf][1], kfr[kf][1], a, 0, 0, 0);
        sv[qf][kf] = a;
      }

    // mask + scale
#pragma unroll
    for (int kf = 0; kf < 4; ++kf) {
      int j = kb + kf * 16 + lc;
      int jr = j >> 5, jcc = j & 31;
#pragma unroll
      for (int qf = 0; qf < 2; ++qf)
#pragma unroll
        for (int r = 0; r < 4; ++r) {
          int p = pb[qf * 4 + r];
          bool ok = ((unsigned)(jr - (p & 255)) <= (unsigned)((p >> 8) & 255)) &&
                    ((unsigned)(jcc - ((p >> 16) & 255)) <= (unsigned)(p >> 24));
          sv[qf][kf][r] = ok ? sv[qf][kf][r] * 0.125f : -3.0e38f;
        }
    }

    // online softmax (row = query lives in 16 lanes of same group g)
#pragma unroll
    for (int qf = 0; qf < 2; ++qf)
#pragma unroll
      for (int r = 0; r < 4; ++r) {
        int idx = qf * 4 + r;
        float tm = fmaxf(fmaxf(sv[qf][0][r], sv[qf][1][r]), fmaxf(sv[qf][2][r], sv[qf][3][r]));
        tm = fmaxf(tm, __shfl_xor(tm, 1));
        tm = fmaxf(tm, __shfl_xor(tm, 2));
        tm = fmaxf(tm, __shfl_xor(tm, 4));
        tm = fmaxf(tm, __shfl_xor(tm, 8));
        float mn = fmaxf(m_run[idx], tm);
        float sc = __expf(m_run[idx] - mn);
        m_run[idx] = mn;
        float ps = 0.0f;
#pragma unroll
        for (int kf = 0; kf < 4; ++kf) {
          float pe = __expf(sv[qf][kf][r] - mn);
          sv[qf][kf][r] = pe;
          ps += pe;
        }
        ps += __shfl_xor(ps, 1); ps += __shfl_xor(ps, 2);
        ps += __shfl_xor(ps, 4); ps += __shfl_xor(ps, 8);
        l_run[idx] = l_run[idx] * sc + ps;
#pragma unroll
        for (int df = 0; df < 4; ++df) po[qf][df][r] *= sc;
      }

    // P (C-layout) -> LDS -> A-layout fragments (wave-private, no barrier needed)
#pragma unroll
    for (int qf = 0; qf < 2; ++qf)
#pragma unroll
      for (int kf = 0; kf < 4; ++kf)
#pragma unroll
        for (int r = 0; r < 4; ++r)
          Plds[w][qf * 16 + g * 4 + r][kf * 16 + lc] = f2bf(sv[qf][kf][r]);

#pragma unroll
    for (int qf = 0; qf < 2; ++qf) {
      bf16x8 pa[2];
#pragma unroll
      for (int kc = 0; kc < 2; ++kc)
        pa[kc] = *(const bf16x8*)(&Plds[w][qf * 16 + lc][kc * 32 + g * 8]);
#pragma unroll
      for (int df = 0; df < 4; ++df) {
        po[qf][df] = __builtin_amdgcn_mfma_f32_16x16x32_bf16(pa[0], vfr[df][0], po[qf][df], 0, 0, 0);
        po[qf][df] = __builtin_amdgcn_mfma_f32_16x16x32_bf16(pa[1], vfr[df][1], po[qf][df], 0, 0, 0);
      }
    }
  }

  // epilogue: normalize, write bf16
#pragma unroll
  for (int qf = 0; qf < 2; ++qf)
#pragma unroll
    for (int r = 0; r < 4; ++r) {
      float inv = 1.0f / l_run[qf * 4 + r];
      long qr = qrow0 + qf * 16 + g * 4 + r;
#pragma unroll
      for (int df = 0; df < 4; ++df)
        Abf[qr * 512 + h * 64 + df * 16 + lc] = f2bf(po[qf][df][r] * inv);
    }
}

extern "C" void kernel_launch(void* const* d_in, const int* in_sizes, int n_in,
                              void* d_out, int out_size, void* d_ws, size_t ws_size,
                              hipStream_t stream) {
  (void)in_sizes; (void)n_in; (void)out_size; (void)ws_size;
  const float* feats   = (const float*)d_in[0];
  const int*   coords  = (const int*)d_in[1];
  const float* ctx     = (const float*)d_in[2];
  const float* Wq      = (const float*)d_in[3];
  const float* Wk      = (const float*)d_in[4];
  const float* Wv      = (const float*)d_in[5];
  const float* Wo      = (const float*)d_in[6];
  const float* bo      = (const float*)d_in[7];
  const float* pos_emb = (const float*)d_in[8];
  const float* ctx_pos = (const float*)d_in[9];
  float* out = (float*)d_out;
  char* ws = (char*)d_ws;

  unsigned short* Aq   = (unsigned short*)(ws);               // 8,388,608
  unsigned short* Actx = (unsigned short*)(ws + 8388608);     // 4,194,304
  unsigned short* Wqt  = (unsigned short*)(ws + 12582912);    //   524,288
  unsigned short* Wkt  = (unsigned short*)(ws + 13107200);
  unsigned short* Wvt  = (unsigned short*)(ws + 13631488);
  unsigned short* Wot  = (unsigned short*)(ws + 14155776);
  unsigned short* Qb   = (unsigned short*)(ws + 14680064);    // 8,388,608
  unsigned short* Kb   = (unsigned short*)(ws + 23068672);    // 4,194,304
  unsigned short* Vb   = (unsigned short*)(ws + 27262976);    // 4,194,304
  unsigned short* Vt   = (unsigned short*)(ws + 31457280);    // 4,194,304
  unsigned short* Abf  = (unsigned short*)(ws + 35651584);    // 8,388,608 (end 44,040,192)

  prep_q  <<<16384, 256, 0, stream>>>(feats, coords, pos_emb, Aq);
  prep_ctx<<< 8192, 256, 0, stream>>>(ctx, ctx_pos, Actx);
  prep_w  <<< 4096, 256, 0, stream>>>(Wq, Wk, Wv, Wo, Wqt, Wkt, Wvt, Wot);

  gemm_bt_bf<<<dim3(64, 4), 256, 0, stream>>>(Aq,   Wqt, Qb);   // Q (bf16)
  gemm_bt_bf<<<dim3(32, 4), 256, 0, stream>>>(Actx, Wkt, Kb);   // K (bf16)
  gemm_bt_bf<<<dim3(32, 4), 256, 0, stream>>>(Actx, Wvt, Vb);   // V (bf16)

  vt_tile<<<512, 256, 0, stream>>>(Vb, Vt);

  attn_mfma<<<dim3(16, 32), 256, 0, stream>>>(Qb, Kb, Vt, coords, Abf);

  gemm_bt<<<dim3(64, 4), 256, 0, stream>>>(Abf, Wot, out, bo);  // O + bias
}